// Round 3
// baseline (787.621 us; speedup 1.0000x reference)
//
#include <hip/hip_runtime.h>
#include <hip/hip_bf16.h>
#include <cstdint>
#include <cstddef>

#define N_F 128
#define N_HOPS 8
#define N_HID 256
#define N_CLS 64

typedef __bf16 bf16;
typedef __attribute__((ext_vector_type(8))) __bf16 bf16x8;
typedef __attribute__((ext_vector_type(4))) float f32x4;

__device__ inline f32x4 mfma16(bf16x8 a, bf16x8 b, f32x4 c) {
    return __builtin_amdgcn_mfma_f32_16x16x32_bf16(a, b, c, 0, 0, 0);
}

typedef const __attribute__((address_space(1))) unsigned int guint;
typedef __attribute__((address_space(3))) unsigned int luint;
__device__ __forceinline__ void gl_lds16(const void* g, void* l) {
    // async global->LDS, 16 B per lane (wave-uniform base + lane*16)
    __builtin_amdgcn_global_load_lds((guint*)g, (luint*)l, 16, 0, 0);
}

// ---------------------------------------------------------------------------
// Weight packing into MFMA B-operand fragment frames (unchanged, verified).
// Frame f = kt*NT + nt holds B[kt*32 .. +32)[nt*16 .. +16):
//   element (lane, j) = W[kt*32 + (lane>>4)*8 + j][nt*16 + (lane&15)]
// stored at d[(f*64 + lane)*8 + j].
// ---------------------------------------------------------------------------
__device__ inline void pack_one(const float* __restrict__ s, bf16* __restrict__ d,
                                int NC, int ntn, int idx) {
    const int lane = idx & 63;
    const int f = idx >> 6;
    const int kt = f / ntn, nt = f - kt * ntn;
    const int krow = kt * 32 + ((lane >> 4) << 3);
    const int col = nt * 16 + (lane & 15);
    const float* ss = s + (size_t)krow * NC + col;
    bf16* dd = d + ((size_t)f * 64 + lane) * 8;
#pragma unroll
    for (int j = 0; j < 8; ++j) dd[j] = (bf16)ss[(size_t)j * NC];
}

__global__ void pack_weights(const float* __restrict__ W1, const float* __restrict__ W2,
                             const float* __restrict__ O1, const float* __restrict__ O2,
                             bf16* p1, bf16* p2, bf16* p3, bf16* p4) {
    int i = blockIdx.x * 256 + threadIdx.x;
    if (i < 32768) { pack_one(W1, p1, 256, 16, i); return; }   // 1024x256: 512 frames
    i -= 32768;
    if (i < 8192)  { pack_one(W2, p2, 256, 16, i); return; }   // 256x256: 128 frames
    i -= 8192;
    if (i < 4096)  { pack_one(O1, p3, 256, 16, i); return; }   // 128x256: 64 frames
    i -= 4096;
    if (i < 2048)  { pack_one(O2, p4, 64, 4, i); return; }     // 256x64: 32 frames
}

// ---------------------------------------------------------------------------
// Fused kernel: 64 rows/block, 256 thr (4 waves).
// Phase 1 (GEMM1): counted-vmcnt 2-barrier pipeline (T3/T4):
//   iter kt: [vmcnt(N) ; s_barrier]  -> buf[kt&1] guaranteed complete,
//            issue A(kt+2) ring-3 prefetch, s_x partial, 16 MFMA,
//            [s_barrier] -> all waves done reading buf[kt&1],
//            issue DMA(kt+2 -> buf[kt&1]).
//   vmcnt is NEVER drained to 0 in the steady loop; B-DMA gets 2 full
//   iterations to land, A global loads ~2 iterations. Counts are static
//   (full unroll): kt=0 -> 4, kt in [1,30] -> 6, kt=31 -> 0.
//   sched_barrier(0) pins region boundaries (vmcnt bookkeeping + no hoist).
// wax lives in LDS so its reads are lgkm-domain (don't perturb vmcnt counts).
// NOTE (R2 lesson): NO min-waves arg in launch_bounds — (256,4) capped VGPR
// at 64 and spilled 230 MB/dispatch to scratch (WRITE_SIZE 25->171 MB).
// Phases 2-6 unchanged from the verified R1 kernel.
// ---------------------------------------------------------------------------
__global__ __launch_bounds__(256) void fused_kernel(
    const float* __restrict__ feats, const bf16* __restrict__ w1p, const bf16* __restrict__ w2p,
    const bf16* __restrict__ o1p, const bf16* __restrict__ o2p,
    const float* __restrict__ b1, const float* __restrict__ b2,
    const float* __restrict__ a_jk_p, const float* __restrict__ a_main_p,
    const float* __restrict__ wref, const float* __restrict__ wax,
    const float* __restrict__ batt_p,
    const float* __restrict__ bo1, const float* __restrict__ a_out_p,
    const float* __restrict__ bo2, float* __restrict__ out, int N)
{
    union __align__(16) U {
        bf16 B[2][8192];     // GEMM1 B double buffer (2 x 16 KB)
        bf16 H[64 * 264];    // h1 row-major (+8 pad)     33792 B
        bf16 AG[64 * 136];   // agg bf16 row-major (+8 pad)
        bf16 HO[64 * 264];   // h_o row-major (+8 pad)
    };
    __shared__ U u;
    __shared__ float sx[64 * 8];
    __shared__ float sref[64];
    __shared__ float waxl[128];

    const int t = threadIdx.x;
    const int lane = t & 63;
    const int wv = t >> 6;
    const int row0 = blockIdx.x * 64;
    const int rA = lane & 15;          // row-in-strip / col-in-tile
    const int cA = lane >> 4;          // k-chunk / row-subgroup

    if (t < 64) sref[t] = 0.f;
    if (t < 128) waxl[t] = wax[t];

    // ---------------- Phase 1: GEMM1  h1 = prelu(concat@W1 + b1) ----------
    const int growA = min(row0 + (wv << 4) + rA, N - 1);
    const float* arow = feats + (size_t)growA * N_F + (cA << 3);
    const size_t hopstride = (size_t)N * N_F;

    f32x4 acc[16] = {};
    float pacc = 0.f;

    float4 bA[3][2];
    // prologue: A(0), A(1) then DMA(0->buf0), DMA(1->buf1)
    bA[0][0] = *(const float4*)(arow);
    bA[0][1] = *(const float4*)(arow + 4);
    bA[1][0] = *(const float4*)(arow + 32);
    bA[1][1] = *(const float4*)(arow + 36);
#pragma unroll
    for (int q = 0; q < 4; ++q)
        gl_lds16(w1p + q * 2048 + t * 8, &u.B[0][q * 2048 + t * 8]);
#pragma unroll
    for (int q = 0; q < 4; ++q)
        gl_lds16(w1p + 8192 + q * 2048 + t * 8, &u.B[1][q * 2048 + t * 8]);

#pragma unroll
    for (int kt = 0; kt < 32; ++kt) {
        const int cur = kt & 1;
        // ---- counted wait: buf[cur] (DMA(kt)) complete; never vmcnt(0) mid-loop ----
        __builtin_amdgcn_sched_barrier(0);
        if (kt == 0)       asm volatile("s_waitcnt vmcnt(4)" ::: "memory");
        else if (kt == 31) asm volatile("s_waitcnt vmcnt(0)" ::: "memory");
        else               asm volatile("s_waitcnt vmcnt(6)" ::: "memory");
        __builtin_amdgcn_s_barrier();
        __builtin_amdgcn_sched_barrier(0);

        // ---- issue A(kt+2) (ring-3 prefetch; ~2 iterations of HBM cover) ----
        if (kt + 2 < 32) {
            const int kn = kt + 2;
            const float* np = arow + (size_t)(kn >> 2) * hopstride + ((kn & 3) << 5);
            bA[(kt + 2) % 3][0] = *(const float4*)np;
            bA[(kt + 2) % 3][1] = *(const float4*)(np + 4);
        }

        // ---- s_x partial (wax from LDS: lgkm domain, vmcnt-neutral) ----
        const float4 v0 = bA[kt % 3][0];
        const float4 v1 = bA[kt % 3][1];
        const int f0 = ((kt & 3) << 5) + (cA << 3);
        const float4 wx0 = *(const float4*)&waxl[f0];
        const float4 wx1 = *(const float4*)&waxl[f0 + 4];
        pacc += v0.x * wx0.x + v0.y * wx0.y + v0.z * wx0.z + v0.w * wx0.w
              + v1.x * wx1.x + v1.y * wx1.y + v1.z * wx1.z + v1.w * wx1.w;
        if ((kt & 3) == 3) {
            pacc += __shfl_xor(pacc, 16, 64);
            pacc += __shfl_xor(pacc, 32, 64);
            if (lane < 16) sx[(((wv << 4) + lane) << 3) + (kt >> 2)] = pacc;
            pacc = 0.f;
        }

        // ---- A-fragment in regs, 16 MFMAs over the 256 output cols ----
        bf16x8 af;
        af[0] = (bf16)v0.x; af[1] = (bf16)v0.y; af[2] = (bf16)v0.z; af[3] = (bf16)v0.w;
        af[4] = (bf16)v1.x; af[5] = (bf16)v1.y; af[6] = (bf16)v1.z; af[7] = (bf16)v1.w;
#pragma unroll
        for (int j = 0; j < 16; ++j) {
            const bf16x8 bfr = *(const bf16x8*)&u.B[cur][((j << 6) + lane) << 3];
            acc[j] = mfma16(af, bfr, acc[j]);
        }

        // ---- all waves done reading buf[cur] -> safe to DMA-overwrite it ----
        __builtin_amdgcn_sched_barrier(0);
        __builtin_amdgcn_s_barrier();
        __builtin_amdgcn_sched_barrier(0);
        if (kt + 2 < 32) {
            const bf16* bsrc = w1p + (size_t)(kt + 2) * 8192;
#pragma unroll
            for (int q = 0; q < 4; ++q)
                gl_lds16(bsrc + q * 2048 + t * 8, &u.B[cur][q * 2048 + t * 8]);
        }
    }

    // ---- epilogue 1: h1 = prelu(acc + b1, a_jk) -> H row-major ----
    const float ajk = *a_jk_p;
#pragma unroll
    for (int j = 0; j < 16; ++j) {
        const int colg = (j << 4) + rA;
        const float bias = b1[colg];
#pragma unroll
        for (int r = 0; r < 4; ++r) {
            const int row = (wv << 4) + (cA << 2) + r;
            float v = acc[j][r] + bias;
            v = v >= 0.f ? v : ajk * v;
            u.H[row * 264 + colg] = (bf16)v;
        }
    }
    __syncthreads();

    // ---- Phase 2: GEMM2 jk = prelu(h1 @ W2 + b2, a_main); sref partials ----
    f32x4 acc2[4][4] = {};
#pragma unroll
    for (int kt = 0; kt < 8; ++kt) {
        bf16x8 af2[4], bfr[4];
#pragma unroll
        for (int i = 0; i < 4; ++i)
            af2[i] = *(bf16x8*)&u.H[((i << 4) + rA) * 264 + (kt << 5) + (cA << 3)];
#pragma unroll
        for (int j = 0; j < 4; ++j)
            bfr[j] = *(const bf16x8*)&w2p[((size_t)((kt << 4) + (wv << 2) + j) * 64 + lane) * 8];
#pragma unroll
        for (int i = 0; i < 4; ++i)
#pragma unroll
            for (int j = 0; j < 4; ++j)
                acc2[i][j] = mfma16(af2[i], bfr[j], acc2[i][j]);
    }

    const float amain = *a_main_p;
    float pr[4][4] = {};
#pragma unroll
    for (int j = 0; j < 4; ++j) {
        const int colg = (wv << 6) + (j << 4) + rA;
        const float bias = b2[colg];
        const float wr_ = wref[colg];
#pragma unroll
        for (int i = 0; i < 4; ++i)
#pragma unroll
            for (int r = 0; r < 4; ++r) {
                float v = acc2[i][j][r] + bias;
                v = v >= 0.f ? v : amain * v;
                pr[i][r] += v * wr_;
            }
    }
#pragma unroll
    for (int m = 1; m < 16; m <<= 1)
#pragma unroll
        for (int i = 0; i < 4; ++i)
#pragma unroll
            for (int r = 0; r < 4; ++r)
                pr[i][r] += __shfl_xor(pr[i][r], m, 64);
    if (rA == 0) {
#pragma unroll
        for (int i = 0; i < 4; ++i)
#pragma unroll
            for (int r = 0; r < 4; ++r)
                atomicAdd(&sref[(i << 4) + (cA << 2) + r], pr[i][r]);
    }
    __syncthreads();

    // ---- Phase 3: scores -> sigmoid -> softmax over hops (stays in LDS) ----
    if (t < 64) {
        const float srf = sref[t] + *batt_p;
        float e[8], mx = -1e30f;
#pragma unroll
        for (int h = 0; h < 8; ++h) {
            const float s = 1.f / (1.f + expf(-(sx[(t << 3) + h] + srf)));
            e[h] = s; mx = fmaxf(mx, s);
        }
        float sum = 0.f;
#pragma unroll
        for (int h = 0; h < 8; ++h) { e[h] = expf(e[h] - mx); sum += e[h]; }
        const float inv = 1.f / sum;
#pragma unroll
        for (int h = 0; h < 8; ++h) sx[(t << 3) + h] = e[h] * inv;
    }
    __syncthreads();

    // ---- Phase 4: weighted hop aggregation (depth-1 hop prefetch) ----
    {
        const int r = t >> 2;              // row 0..63
        const int c = t & 3;               // 32-feature chunk
        const int rg = min(row0 + r, N - 1);
        const float* bp = feats + (size_t)rg * N_F + (c << 5);
        f32x4 a4[8] = {};
        f32x4 pA[8], pB[8];
#pragma unroll
        for (int q = 0; q < 8; ++q) pA[q] = ((const f32x4*)bp)[q];
#pragma unroll
        for (int h = 0; h < 8; ++h) {
            if (h < 7) {
                const f32x4* np = (const f32x4*)(bp + hopstride * (h + 1));
#pragma unroll
                for (int q = 0; q < 8; ++q) pB[q] = np[q];
            }
            const float wgt = sx[(r << 3) + h];
#pragma unroll
            for (int q = 0; q < 8; ++q) a4[q] += wgt * pA[q];
            if (h < 7) {
#pragma unroll
                for (int q = 0; q < 8; ++q) pA[q] = pB[q];
            }
        }
#pragma unroll
        for (int q2 = 0; q2 < 4; ++q2) {
            bf16x8 av;
#pragma unroll
            for (int e2 = 0; e2 < 4; ++e2) {
                av[e2] = (bf16)a4[q2 * 2][e2];
                av[4 + e2] = (bf16)a4[q2 * 2 + 1][e2];
            }
            *(bf16x8*)&u.AG[r * 136 + (c << 5) + q2 * 8] = av;
        }
    }
    __syncthreads();

    // ---- Phase 5: GEMM3 h_o = prelu(agg @ O1 + bo1, a_out) [K=128] ----
    f32x4 acc3[4][4] = {};
#pragma unroll
    for (int kt = 0; kt < 4; ++kt) {
        bf16x8 af3[4], bfr[4];
#pragma unroll
        for (int i = 0; i < 4; ++i)
            af3[i] = *(bf16x8*)&u.AG[((i << 4) + rA) * 136 + (kt << 5) + (cA << 3)];
#pragma unroll
        for (int j = 0; j < 4; ++j)
            bfr[j] = *(const bf16x8*)&o1p[((size_t)((kt << 4) + (wv << 2) + j) * 64 + lane) * 8];
#pragma unroll
        for (int i = 0; i < 4; ++i)
#pragma unroll
            for (int j = 0; j < 4; ++j)
                acc3[i][j] = mfma16(af3[i], bfr[j], acc3[i][j]);
    }
    __syncthreads();   // all AG reads done before HO overwrites the union

    const float aout = *a_out_p;
#pragma unroll
    for (int j = 0; j < 4; ++j) {
        const int colg = (wv << 6) + (j << 4) + rA;
        const float bias = bo1[colg];
#pragma unroll
        for (int i = 0; i < 4; ++i)
#pragma unroll
            for (int r = 0; r < 4; ++r) {
                const int row = (i << 4) + (cA << 2) + r;
                float v = acc3[i][j][r] + bias;
                v = v >= 0.f ? v : aout * v;
                u.HO[row * 264 + colg] = (bf16)v;
            }
    }
    __syncthreads();

    // ---- Phase 6: GEMM4 out = h_o @ O2 + bo2 [K=256; wave -> 16 cols] ----
    f32x4 acc4[4] = {};
#pragma unroll
    for (int kt = 0; kt < 8; ++kt) {
        const bf16x8 b = *(const bf16x8*)&o2p[((size_t)((kt << 2) + wv) * 64 + lane) * 8];
#pragma unroll
        for (int i = 0; i < 4; ++i) {
            const bf16x8 a = *(bf16x8*)&u.HO[((i << 4) + rA) * 264 + (kt << 5) + (cA << 3)];
            acc4[i] = mfma16(a, b, acc4[i]);
        }
    }
    {
        const int colg = (wv << 4) + rA;
        const float bv = bo2[colg];
#pragma unroll
        for (int i = 0; i < 4; ++i)
#pragma unroll
            for (int r = 0; r < 4; ++r) {
                const int rg = row0 + (i << 4) + (cA << 2) + r;
                if (rg < N) out[(size_t)rg * 64 + colg] = acc4[i][r] + bv;
            }
    }
}

extern "C" void kernel_launch(void* const* d_in, const int* in_sizes, int n_in,
                              void* d_out, int out_size, void* d_ws, size_t ws_size,
                              hipStream_t stream) {
    const float* feats  = (const float*)d_in[0];
    const float* W1     = (const float*)d_in[1];
    const float* b1     = (const float*)d_in[2];
    const float* W2     = (const float*)d_in[3];
    const float* b2     = (const float*)d_in[4];
    const float* a_jk   = (const float*)d_in[5];
    const float* a_main = (const float*)d_in[6];
    const float* a_out  = (const float*)d_in[7];
    const float* wref   = (const float*)d_in[8];
    const float* wax    = (const float*)d_in[9];
    const float* batt   = (const float*)d_in[10];
    const float* O1     = (const float*)d_in[11];
    const float* bo1    = (const float*)d_in[12];
    const float* O2     = (const float*)d_in[13];
    const float* bo2    = (const float*)d_in[14];

    const int N = in_sizes[0] / (N_HOPS * N_F);

    char* ws = (char*)d_ws;
    bf16* p1 = (bf16*)ws;                   // 524288 B  (W_jk1 packed)
    bf16* p2 = (bf16*)(ws + 524288);        // 131072 B  (W_jk2 packed)
    bf16* p3 = (bf16*)(ws + 655360);        // 65536 B   (W_o1 packed)
    bf16* p4 = (bf16*)(ws + 720896);        // 32768 B   (W_o2 packed)

    pack_weights<<<184, 256, 0, stream>>>(W1, W2, O1, O2, p1, p2, p3, p4);
    const int nb = (N + 63) / 64;
    fused_kernel<<<nb, 256, 0, stream>>>(feats, p1, p2, p3, p4, b1, b2,
                                         a_jk, a_main, wref, wax, batt,
                                         bo1, a_out, bo2, (float*)d_out, N);
}

// Round 4
// 714.686 us; speedup vs baseline: 1.1021x; 1.1021x over previous
//
#include <hip/hip_runtime.h>
#include <hip/hip_bf16.h>
#include <cstdint>
#include <cstddef>

#define N_F 128
#define N_HOPS 8
#define N_HID 256
#define N_CLS 64

typedef __bf16 bf16;
typedef __attribute__((ext_vector_type(8))) __bf16 bf16x8;
typedef __attribute__((ext_vector_type(4))) float f32x4;

__device__ inline f32x4 mfma16(bf16x8 a, bf16x8 b, f32x4 c) {
    return __builtin_amdgcn_mfma_f32_16x16x32_bf16(a, b, c, 0, 0, 0);
}

typedef const __attribute__((address_space(1))) unsigned int guint;
typedef __attribute__((address_space(3))) unsigned int luint;
__device__ __forceinline__ void gl_lds16(const void* g, void* l) {
    // async global->LDS, 16 B per lane (wave-uniform base + lane*16)
    __builtin_amdgcn_global_load_lds((guint*)g, (luint*)l, 16, 0, 0);
}

// ---------------------------------------------------------------------------
// Weight packing into MFMA B-operand fragment frames (unchanged, verified).
// Frame f = kt*NT + nt holds B[kt*32 .. +32)[nt*16 .. +16):
//   element (lane, j) = W[kt*32 + (lane>>4)*8 + j][nt*16 + (lane&15)]
// stored at d[(f*64 + lane)*8 + j].
// ---------------------------------------------------------------------------
__device__ inline void pack_one(const float* __restrict__ s, bf16* __restrict__ d,
                                int NC, int ntn, int idx) {
    const int lane = idx & 63;
    const int f = idx >> 6;
    const int kt = f / ntn, nt = f - kt * ntn;
    const int krow = kt * 32 + ((lane >> 4) << 3);
    const int col = nt * 16 + (lane & 15);
    const float* ss = s + (size_t)krow * NC + col;
    bf16* dd = d + ((size_t)f * 64 + lane) * 8;
#pragma unroll
    for (int j = 0; j < 8; ++j) dd[j] = (bf16)ss[(size_t)j * NC];
}

__global__ void pack_weights(const float* __restrict__ W1, const float* __restrict__ W2,
                             const float* __restrict__ O1, const float* __restrict__ O2,
                             bf16* p1, bf16* p2, bf16* p3, bf16* p4) {
    int i = blockIdx.x * 256 + threadIdx.x;
    if (i < 32768) { pack_one(W1, p1, 256, 16, i); return; }   // 1024x256: 512 frames
    i -= 32768;
    if (i < 8192)  { pack_one(W2, p2, 256, 16, i); return; }   // 256x256: 128 frames
    i -= 8192;
    if (i < 4096)  { pack_one(O1, p3, 256, 16, i); return; }   // 128x256: 64 frames
    i -= 4096;
    if (i < 2048)  { pack_one(O2, p4, 64, 4, i); return; }     // 256x64: 32 frames
}

// ---------------------------------------------------------------------------
// Fused kernel: 64 rows/block, 256 thr (4 waves).
// Phase 1 (GEMM1): register-lean counted-vmcnt pipeline (R4):
//   iter kt: [s_waitcnt vmcnt(2) lgkmcnt(0) ; s_barrier]
//              -> DMA(kt) (the 4 OLDEST vmem ops) retired: buf[kt&1] ready;
//                 the 2 A(kt) loads may still be in flight (compiler inserts
//                 its own counted wait at their use -> ~1.5 iterations cover).
//            issue DMA(kt+1 -> buf[cur^1])  [FIRST: must stay oldest in queue]
//            issue A(kt+1) reg prefetch     [after: sched_barrier-pinned order]
//            s_x partial, 16 MFMA from buf[cur].
//   ONE barrier per kt, uniform vmcnt(2), never a full drain in the loop.
// R2 lesson: no min-waves clamp (spill). R3 lesson: stay <=128 VGPR — the
// ring-3 A-buffer + 2-barrier structure hit 136 VGPR -> 3 waves/SIMD ->
// occupancy 10.5% and a net regression. This keeps R1's 2-slot A ring.
// wax lives in LDS so its reads are lgkm-domain (vmcnt-count-neutral).
// Phases 2-6 unchanged from the verified R1 kernel.
// ---------------------------------------------------------------------------
__global__ __launch_bounds__(256) void fused_kernel(
    const float* __restrict__ feats, const bf16* __restrict__ w1p, const bf16* __restrict__ w2p,
    const bf16* __restrict__ o1p, const bf16* __restrict__ o2p,
    const float* __restrict__ b1, const float* __restrict__ b2,
    const float* __restrict__ a_jk_p, const float* __restrict__ a_main_p,
    const float* __restrict__ wref, const float* __restrict__ wax,
    const float* __restrict__ batt_p,
    const float* __restrict__ bo1, const float* __restrict__ a_out_p,
    const float* __restrict__ bo2, float* __restrict__ out, int N)
{
    union __align__(16) U {
        bf16 B[2][8192];     // GEMM1 B double buffer (2 x 16 KB)
        bf16 H[64 * 264];    // h1 row-major (+8 pad)     33792 B
        bf16 AG[64 * 136];   // agg bf16 row-major (+8 pad)
        bf16 HO[64 * 264];   // h_o row-major (+8 pad)
    };
    __shared__ U u;
    __shared__ float sx[64 * 8];
    __shared__ float sref[64];
    __shared__ float waxl[128];

    const int t = threadIdx.x;
    const int lane = t & 63;
    const int wv = t >> 6;
    const int row0 = blockIdx.x * 64;
    const int rA = lane & 15;          // row-in-strip / col-in-tile
    const int cA = lane >> 4;          // k-chunk / row-subgroup

    if (t < 64) sref[t] = 0.f;
    if (t < 128) waxl[t] = wax[t];

    // ---------------- Phase 1: GEMM1  h1 = prelu(concat@W1 + b1) ----------
    const int growA = min(row0 + (wv << 4) + rA, N - 1);
    const float* arow = feats + (size_t)growA * N_F + (cA << 3);
    const size_t hopstride = (size_t)N * N_F;

    f32x4 acc[16] = {};
    float pacc = 0.f;

    // prologue: DMA(0 -> buf0) FIRST (oldest in vmcnt queue), then A(0) regs
#pragma unroll
    for (int q = 0; q < 4; ++q)
        gl_lds16(w1p + q * 2048 + t * 8, &u.B[0][q * 2048 + t * 8]);
    __builtin_amdgcn_sched_barrier(0);
    float4 v0 = *(const float4*)(arow);
    float4 v1 = *(const float4*)(arow + 4);

#pragma unroll 2
    for (int kt = 0; kt < 32; ++kt) {
        const int cur = kt & 1;
        // ---- counted wait: DMA(kt) retired (4 oldest); A(kt) may stay in flight ----
        __builtin_amdgcn_sched_barrier(0);
        asm volatile("s_waitcnt vmcnt(2) lgkmcnt(0)" ::: "memory");
        __builtin_amdgcn_s_barrier();
        __builtin_amdgcn_sched_barrier(0);

        // ---- issue DMA(kt+1 -> buf[cur^1]) FIRST (stays oldest in queue) ----
        if (kt < 31) {
            const bf16* bsrc = w1p + (size_t)(kt + 1) * 8192;
#pragma unroll
            for (int q = 0; q < 4; ++q)
                gl_lds16(bsrc + q * 2048 + t * 8, &u.B[cur ^ 1][q * 2048 + t * 8]);
        }
        __builtin_amdgcn_sched_barrier(0);

        // ---- issue A(kt+1) register prefetch ----
        float4 v0n, v1n;
        if (kt < 31) {
            const int kn = kt + 1;
            const float* np = arow + (size_t)(kn >> 2) * hopstride + ((kn & 3) << 5);
            v0n = *(const float4*)np;
            v1n = *(const float4*)(np + 4);
        }
        __builtin_amdgcn_sched_barrier(0);

        // ---- s_x partial (wax from LDS: lgkm domain, vmcnt-neutral) ----
        const int f0 = ((kt & 3) << 5) + (cA << 3);
        const float4 wx0 = *(const float4*)&waxl[f0];
        const float4 wx1 = *(const float4*)&waxl[f0 + 4];
        pacc += v0.x * wx0.x + v0.y * wx0.y + v0.z * wx0.z + v0.w * wx0.w
              + v1.x * wx1.x + v1.y * wx1.y + v1.z * wx1.z + v1.w * wx1.w;
        if ((kt & 3) == 3) {
            pacc += __shfl_xor(pacc, 16, 64);
            pacc += __shfl_xor(pacc, 32, 64);
            if (lane < 16) sx[(((wv << 4) + lane) << 3) + (kt >> 2)] = pacc;
            pacc = 0.f;
        }

        // ---- A-fragment in regs, 16 MFMAs over the 256 output cols ----
        bf16x8 af;
        af[0] = (bf16)v0.x; af[1] = (bf16)v0.y; af[2] = (bf16)v0.z; af[3] = (bf16)v0.w;
        af[4] = (bf16)v1.x; af[5] = (bf16)v1.y; af[6] = (bf16)v1.z; af[7] = (bf16)v1.w;
#pragma unroll
        for (int j = 0; j < 16; ++j) {
            const bf16x8 bfr = *(const bf16x8*)&u.B[cur][((j << 6) + lane) << 3];
            acc[j] = mfma16(af, bfr, acc[j]);
        }

        if (kt < 31) { v0 = v0n; v1 = v1n; }
    }
    __syncthreads();   // all B-buffer reads done before H overwrites the union

    // ---- epilogue 1: h1 = prelu(acc + b1, a_jk) -> H row-major ----
    const float ajk = *a_jk_p;
#pragma unroll
    for (int j = 0; j < 16; ++j) {
        const int colg = (j << 4) + rA;
        const float bias = b1[colg];
#pragma unroll
        for (int r = 0; r < 4; ++r) {
            const int row = (wv << 4) + (cA << 2) + r;
            float v = acc[j][r] + bias;
            v = v >= 0.f ? v : ajk * v;
            u.H[row * 264 + colg] = (bf16)v;
        }
    }
    __syncthreads();

    // ---- Phase 2: GEMM2 jk = prelu(h1 @ W2 + b2, a_main); sref partials ----
    f32x4 acc2[4][4] = {};
#pragma unroll
    for (int kt = 0; kt < 8; ++kt) {
        bf16x8 af2[4], bfr[4];
#pragma unroll
        for (int i = 0; i < 4; ++i)
            af2[i] = *(bf16x8*)&u.H[((i << 4) + rA) * 264 + (kt << 5) + (cA << 3)];
#pragma unroll
        for (int j = 0; j < 4; ++j)
            bfr[j] = *(const bf16x8*)&w2p[((size_t)((kt << 4) + (wv << 2) + j) * 64 + lane) * 8];
#pragma unroll
        for (int i = 0; i < 4; ++i)
#pragma unroll
            for (int j = 0; j < 4; ++j)
                acc2[i][j] = mfma16(af2[i], bfr[j], acc2[i][j]);
    }

    const float amain = *a_main_p;
    float pr[4][4] = {};
#pragma unroll
    for (int j = 0; j < 4; ++j) {
        const int colg = (wv << 6) + (j << 4) + rA;
        const float bias = b2[colg];
        const float wr_ = wref[colg];
#pragma unroll
        for (int i = 0; i < 4; ++i)
#pragma unroll
            for (int r = 0; r < 4; ++r) {
                float v = acc2[i][j][r] + bias;
                v = v >= 0.f ? v : amain * v;
                pr[i][r] += v * wr_;
            }
    }
#pragma unroll
    for (int m = 1; m < 16; m <<= 1)
#pragma unroll
        for (int i = 0; i < 4; ++i)
#pragma unroll
            for (int r = 0; r < 4; ++r)
                pr[i][r] += __shfl_xor(pr[i][r], m, 64);
    if (rA == 0) {
#pragma unroll
        for (int i = 0; i < 4; ++i)
#pragma unroll
            for (int r = 0; r < 4; ++r)
                atomicAdd(&sref[(i << 4) + (cA << 2) + r], pr[i][r]);
    }
    __syncthreads();

    // ---- Phase 3: scores -> sigmoid -> softmax over hops (stays in LDS) ----
    if (t < 64) {
        const float srf = sref[t] + *batt_p;
        float e[8], mx = -1e30f;
#pragma unroll
        for (int h = 0; h < 8; ++h) {
            const float s = 1.f / (1.f + expf(-(sx[(t << 3) + h] + srf)));
            e[h] = s; mx = fmaxf(mx, s);
        }
        float sum = 0.f;
#pragma unroll
        for (int h = 0; h < 8; ++h) { e[h] = expf(e[h] - mx); sum += e[h]; }
        const float inv = 1.f / sum;
#pragma unroll
        for (int h = 0; h < 8; ++h) sx[(t << 3) + h] = e[h] * inv;
    }
    __syncthreads();

    // ---- Phase 4: weighted hop aggregation (depth-1 hop prefetch) ----
    {
        const int r = t >> 2;              // row 0..63
        const int c = t & 3;               // 32-feature chunk
        const int rg = min(row0 + r, N - 1);
        const float* bp = feats + (size_t)rg * N_F + (c << 5);
        f32x4 a4[8] = {};
        f32x4 pA[8], pB[8];
#pragma unroll
        for (int q = 0; q < 8; ++q) pA[q] = ((const f32x4*)bp)[q];
#pragma unroll
        for (int h = 0; h < 8; ++h) {
            if (h < 7) {
                const f32x4* np = (const f32x4*)(bp + hopstride * (h + 1));
#pragma unroll
                for (int q = 0; q < 8; ++q) pB[q] = np[q];
            }
            const float wgt = sx[(r << 3) + h];
#pragma unroll
            for (int q = 0; q < 8; ++q) a4[q] += wgt * pA[q];
            if (h < 7) {
#pragma unroll
                for (int q = 0; q < 8; ++q) pA[q] = pB[q];
            }
        }
#pragma unroll
        for (int q2 = 0; q2 < 4; ++q2) {
            bf16x8 av;
#pragma unroll
            for (int e2 = 0; e2 < 4; ++e2) {
                av[e2] = (bf16)a4[q2 * 2][e2];
                av[4 + e2] = (bf16)a4[q2 * 2 + 1][e2];
            }
            *(bf16x8*)&u.AG[r * 136 + (c << 5) + q2 * 8] = av;
        }
    }
    __syncthreads();

    // ---- Phase 5: GEMM3 h_o = prelu(agg @ O1 + bo1, a_out) [K=128] ----
    f32x4 acc3[4][4] = {};
#pragma unroll
    for (int kt = 0; kt < 4; ++kt) {
        bf16x8 af3[4], bfr[4];
#pragma unroll
        for (int i = 0; i < 4; ++i)
            af3[i] = *(bf16x8*)&u.AG[((i << 4) + rA) * 136 + (kt << 5) + (cA << 3)];
#pragma unroll
        for (int j = 0; j < 4; ++j)
            bfr[j] = *(const bf16x8*)&o1p[((size_t)((kt << 4) + (wv << 2) + j) * 64 + lane) * 8];
#pragma unroll
        for (int i = 0; i < 4; ++i)
#pragma unroll
            for (int j = 0; j < 4; ++j)
                acc3[i][j] = mfma16(af3[i], bfr[j], acc3[i][j]);
    }
    __syncthreads();   // all AG reads done before HO overwrites the union

    const float aout = *a_out_p;
#pragma unroll
    for (int j = 0; j < 4; ++j) {
        const int colg = (wv << 6) + (j << 4) + rA;
        const float bias = bo1[colg];
#pragma unroll
        for (int i = 0; i < 4; ++i)
#pragma unroll
            for (int r = 0; r < 4; ++r) {
                const int row = (i << 4) + (cA << 2) + r;
                float v = acc3[i][j][r] + bias;
                v = v >= 0.f ? v : aout * v;
                u.HO[row * 264 + colg] = (bf16)v;
            }
    }
    __syncthreads();

    // ---- Phase 6: GEMM4 out = h_o @ O2 + bo2 [K=256; wave -> 16 cols] ----
    f32x4 acc4[4] = {};
#pragma unroll
    for (int kt = 0; kt < 8; ++kt) {
        const bf16x8 b = *(const bf16x8*)&o2p[((size_t)((kt << 2) + wv) * 64 + lane) * 8];
#pragma unroll
        for (int i = 0; i < 4; ++i) {
            const bf16x8 a = *(bf16x8*)&u.HO[((i << 4) + rA) * 264 + (kt << 5) + (cA << 3)];
            acc4[i] = mfma16(a, b, acc4[i]);
        }
    }
    {
        const int colg = (wv << 4) + rA;
        const float bv = bo2[colg];
#pragma unroll
        for (int i = 0; i < 4; ++i)
#pragma unroll
            for (int r = 0; r < 4; ++r) {
                const int rg = row0 + (i << 4) + (cA << 2) + r;
                if (rg < N) out[(size_t)rg * 64 + colg] = acc4[i][r] + bv;
            }
    }
}

extern "C" void kernel_launch(void* const* d_in, const int* in_sizes, int n_in,
                              void* d_out, int out_size, void* d_ws, size_t ws_size,
                              hipStream_t stream) {
    const float* feats  = (const float*)d_in[0];
    const float* W1     = (const float*)d_in[1];
    const float* b1     = (const float*)d_in[2];
    const float* W2     = (const float*)d_in[3];
    const float* b2     = (const float*)d_in[4];
    const float* a_jk   = (const float*)d_in[5];
    const float* a_main = (const float*)d_in[6];
    const float* a_out  = (const float*)d_in[7];
    const float* wref   = (const float*)d_in[8];
    const float* wax    = (const float*)d_in[9];
    const float* batt   = (const float*)d_in[10];
    const float* O1     = (const float*)d_in[11];
    const float* bo1    = (const float*)d_in[12];
    const float* O2     = (const float*)d_in[13];
    const float* bo2    = (const float*)d_in[14];

    const int N = in_sizes[0] / (N_HOPS * N_F);

    char* ws = (char*)d_ws;
    bf16* p1 = (bf16*)ws;                   // 524288 B  (W_jk1 packed)
    bf16* p2 = (bf16*)(ws + 524288);        // 131072 B  (W_jk2 packed)
    bf16* p3 = (bf16*)(ws + 655360);        // 65536 B   (W_o1 packed)
    bf16* p4 = (bf16*)(ws + 720896);        // 32768 B   (W_o2 packed)

    pack_weights<<<184, 256, 0, stream>>>(W1, W2, O1, O2, p1, p2, p3, p4);
    const int nb = (N + 63) / 64;
    fused_kernel<<<nb, 256, 0, stream>>>(feats, p1, p2, p3, p4, b1, b2,
                                         a_jk, a_main, wref, wax, batt,
                                         bo1, a_out, bo2, (float*)d_out, N);
}